// Round 6
// baseline (363.842 us; speedup 1.0000x reference)
//
#include <hip/hip_runtime.h>
#include <math.h>

// ---------------- problem constants ----------------
#define BATCH   256
#define NCLS    10
#define DIM     48

// ---------------- workspace layout (float elements) ----------------
// h1 [0, 7372800) is live conv1->conv2 only. wT ALIASES h1 and MUST be
// written only after conv2 completes (separate k_wtrans launch). pairm/fc1p
// also alias h1 (written after conv2).
#define OFF_H1    0            // 256*32*30*30 = 7372800 (conv1 out)
#define OFF_PAIR  0            // 256*2304 = 589824      (written by k_fc23a)
#define OFF_FC1P  602112       // 64*256*128 = 2097152   (ends 2699264)
#define OFF_WT    2699264      // 12544*128 = 1605632    (ends 4304896)
#define OFF_POOL  7372800      // 256*12544 = 3211264
#define OFF_DO    10596352     // 256*48
#define OFF_CW    10608640     // 16
#define OFF_INT   10608656     // ints: cls_cnt[16], cls_idx[2560]

// ---------------- signed-root helpers ----------------
__device__ __forceinline__ float sroot_half(float m) {
    float s = (m < 0.f) ? -1.f : 1.f;
    return s * (sqrtf(fabsf(m) + 0.25f) - 0.5f);
}
__device__ __forceinline__ float sroot_cbrt(float m) {
    float s = (m < 0.f) ? -1.f : 1.f;
    return s * (cbrtf(fabsf(m) + 0.19245008973f) - 0.57735026919f);
}
__device__ __forceinline__ float sroot_quarter(float m) {
    float s = (m < 0.f) ? -1.f : 1.f;
    return s * (sqrtf(sqrtf(fabsf(m) + 0.15749013123f)) - 0.62996052494f);
}

// ------- conv1 + relu (4 outputs/thread, 2x2) + folded init -------
__global__ void k_conv1(const float* __restrict__ x, const float* __restrict__ w,
                        const float* __restrict__ bias, float* __restrict__ h1,
                        float* __restrict__ cw, int* __restrict__ cls_cnt,
                        float* __restrict__ out) {
    int blk = blockIdx.x;
    int tid = threadIdx.x;
    if (blk == 0) {
        if (tid < 16) { cw[tid] = 0.f; cls_cnt[tid] = 0; }
        else if (tid < 20) out[2560 + tid - 16] = 0.f;
    }
    int idx = blk * 256 + tid;             // [0, 1843200)
    int q = idx % 225; int qx = q % 15, qy = q / 15;
    int t = idx / 225; int oc = t % 32; int b = t / 32;
    int ox = 2 * qx, oy = 2 * qy;
    float bv = bias[oc];
    float a00 = bv, a01 = bv, a10 = bv, a11 = bv;
    const float* wo = w + oc * 27;
#pragma unroll
    for (int ic = 0; ic < 3; ic++) {
        const float* xp = x + b * 3072 + ic * 1024 + oy * 32 + ox;
        float row[4][4];
#pragma unroll
        for (int r = 0; r < 4; r++) {
            float2 u0 = *(const float2*)(xp + r * 32);
            float2 u1 = *(const float2*)(xp + r * 32 + 2);
            row[r][0] = u0.x; row[r][1] = u0.y; row[r][2] = u1.x; row[r][3] = u1.y;
        }
        const float* wp = wo + ic * 9;
#pragma unroll
        for (int ky = 0; ky < 3; ky++)
#pragma unroll
            for (int kx = 0; kx < 3; kx++) {
                float wv = wp[ky * 3 + kx];
                a00 = fmaf(row[ky][kx],     wv, a00);
                a01 = fmaf(row[ky][kx + 1], wv, a01);
                a10 = fmaf(row[ky + 1][kx],     wv, a10);
                a11 = fmaf(row[ky + 1][kx + 1], wv, a11);
            }
    }
    float* hp = h1 + b * 28800 + oc * 900 + oy * 30 + ox;
    *(float2*)hp        = make_float2(fmaxf(a00, 0.f), fmaxf(a01, 0.f));
    *(float2*)(hp + 30) = make_float2(fmaxf(a10, 0.f), fmaxf(a11, 0.f));
}

// -------- conv2 + relu + 2x2 maxpool: 8 oc/thread, input software-pipelined --------
__global__ __launch_bounds__(256, 6)
void k_conv2(const float* __restrict__ h1, const float* __restrict__ w,
             const float* __restrict__ bias, float* __restrict__ pooled) {
    int blk = blockIdx.x;                 // 1568 blocks
    int ocg = blk / 196;                  // 0..7, block-uniform
    int rem = blk % 196;
    int idx = rem * 256 + threadIdx.x;    // [0, 50176)
    int b = idx / 196;
    int px = idx % 196;
    int py = px / 14, pxx = px % 14;
    int ocb = ocg * 8;
    float acc[8][4];
#pragma unroll
    for (int a = 0; a < 8; a++)
#pragma unroll
        for (int e = 0; e < 4; e++) acc[a][e] = 0.f;
    const float* hb = h1 + b * 28800 + (2 * py) * 30 + 2 * pxx;
    float in_c[4][4], in_n[4][4];
#pragma unroll
    for (int r = 0; r < 4; r++) {
        float2 u0 = *(const float2*)(hb + r * 30);
        float2 u1 = *(const float2*)(hb + r * 30 + 2);
        in_c[r][0] = u0.x; in_c[r][1] = u0.y; in_c[r][2] = u1.x; in_c[r][3] = u1.y;
    }
#pragma unroll 2
    for (int ic = 0; ic < 32; ic++) {
        if (ic < 31) {
            const float* hp = hb + (ic + 1) * 900;
#pragma unroll
            for (int r = 0; r < 4; r++) {
                float2 u0 = *(const float2*)(hp + r * 30);
                float2 u1 = *(const float2*)(hp + r * 30 + 2);
                in_n[r][0] = u0.x; in_n[r][1] = u0.y; in_n[r][2] = u1.x; in_n[r][3] = u1.y;
            }
        }
        const float* wic = w + ocb * 288 + ic * 9;
#pragma unroll
        for (int a = 0; a < 8; a++) {
            const float* wp = wic + a * 288;
#pragma unroll
            for (int ky = 0; ky < 3; ky++)
#pragma unroll
                for (int kx = 0; kx < 3; kx++) {
                    float wv = wp[ky * 3 + kx];
                    acc[a][0] = fmaf(wv, in_c[ky][kx],         acc[a][0]);
                    acc[a][1] = fmaf(wv, in_c[ky][kx + 1],     acc[a][1]);
                    acc[a][2] = fmaf(wv, in_c[ky + 1][kx],     acc[a][2]);
                    acc[a][3] = fmaf(wv, in_c[ky + 1][kx + 1], acc[a][3]);
                }
        }
#pragma unroll
        for (int r = 0; r < 4; r++)
#pragma unroll
            for (int cc = 0; cc < 4; cc++)
                in_c[r][cc] = in_n[r][cc];
    }
#pragma unroll
    for (int a = 0; a < 8; a++) {
        int oc = ocb + a;
        float v = fmaxf(fmaxf(acc[a][0], acc[a][1]), fmaxf(acc[a][2], acc[a][3])) + bias[oc];
        pooled[b * 12544 + oc * 196 + px] = fmaxf(v, 0.f);
    }
}

// ---------------- W transpose: wT[k][n] = w[n][k] (AFTER conv2: wT aliases h1) ----------------
__global__ void k_wtrans(const float* __restrict__ w, float* __restrict__ wT) {
    __shared__ float tile[32][33];
    int kb = blockIdx.x % 392, nb = blockIdx.x / 392;
    int tid = threadIdx.x;
    int tx = tid & 31, ty = tid >> 5;
    int k0 = kb * 32, n0 = nb * 32;
#pragma unroll
    for (int r = 0; r < 4; r++)
        tile[tx][ty * 4 + r] = w[(n0 + ty * 4 + r) * 12544 + k0 + tx];
    __syncthreads();
#pragma unroll
    for (int r = 0; r < 4; r++)
        wT[(k0 + ty * 4 + r) * 128 + n0 + tx] = tile[ty * 4 + r][tx];
}

// ---------------- fc1 K-split GEMM, coalesced W via wT, broadcast A ----------------
__global__ void k_fc1(const float* __restrict__ pooled, const float* __restrict__ wT,
                      float* __restrict__ fc1p) {
    __shared__ __align__(16) float Alds[16 * 196];   // 12.5 KB
    int blk = blockIdx.x;
    int sg = blk >> 6, kc = blk & 63;
    int tid = threadIdx.x;
    int m0 = sg * 16, k0 = kc * 196;
    for (int i = tid; i < 784; i += 256) {           // 16 rows * 49 float4
        int m = i / 49, u = i % 49;
        ((float4*)Alds)[m * 49 + u] = ((const float4*)(pooled + (m0 + m) * 12544 + k0))[u];
    }
    __syncthreads();
    int n2 = tid & 63, mg = tid >> 6;
    const float* wp = wT + (size_t)k0 * 128 + n2;
    const float* arow = Alds + mg * 4 * 196;
    float acc[4][2];
#pragma unroll
    for (int j = 0; j < 4; j++) { acc[j][0] = 0.f; acc[j][1] = 0.f; }
    for (int k = 0; k < 196; k += 2) {
        float wa0 = wp[k * 128],        wb0 = wp[k * 128 + 64];
        float wa1 = wp[(k + 1) * 128],  wb1 = wp[(k + 1) * 128 + 64];
#pragma unroll
        for (int j = 0; j < 4; j++) {
            float2 av = *(const float2*)(arow + j * 196 + k);
            acc[j][0] = fmaf(av.x, wa0, acc[j][0]);
            acc[j][0] = fmaf(av.y, wa1, acc[j][0]);
            acc[j][1] = fmaf(av.x, wb0, acc[j][1]);
            acc[j][1] = fmaf(av.y, wb1, acc[j][1]);
        }
    }
#pragma unroll
    for (int j = 0; j < 4; j++) {
        int m = m0 + mg * 4 + j;
        fc1p[kc * 32768 + m * 128 + n2]      = acc[j][0];
        fc1p[kc * 32768 + m * 128 + n2 + 64] = acc[j][1];
    }
}

// ------- fc1-reduce + fc2 + fc3 + assignment + pair row, fused per-sample -------
__global__ void k_fc23a(const float* __restrict__ fc1p, const float* __restrict__ f1b,
                        const float* __restrict__ w2, const float* __restrict__ b2,
                        const float* __restrict__ w3, const float* __restrict__ b3,
                        const float* __restrict__ centers, float* __restrict__ out,
                        float* __restrict__ dov, float* __restrict__ pairm,
                        float* __restrict__ cw, int* __restrict__ cls_cnt,
                        int* __restrict__ cls_idx) {
    __shared__ float a[128], h[128], zb[48], dvs[48];
    __shared__ float dist[10];
    __shared__ float smn, ssum;
    __shared__ int sarg;
    int b = blockIdx.x, t = threadIdx.x;
    float s0 = f1b[t];
    for (int p = 0; p < 64; p++) s0 += fc1p[p * 32768 + b * 128 + t];
    a[t] = fmaxf(s0, 0.f);
    __syncthreads();
    float s = b2[t];
    const float* wr = w2 + t * 128;
#pragma unroll 4
    for (int k = 0; k < 128; k++) s = fmaf(wr[k], a[k], s);
    h[t] = fmaxf(s, 0.f);
    __syncthreads();
    if (t < 48) {
        float s3 = b3[t];
        const float* wr3 = w3 + t * 128;
#pragma unroll 4
        for (int k = 0; k < 128; k++) s3 = fmaf(wr3[k], h[k], s3);
        zb[t] = s3;
    }
    __syncthreads();
    if (t < 10) {
        float d = 0.f;
        const float* cc = centers + t * 48;
        for (int k = 0; k < 48; k++) { float df = zb[k] - cc[k]; d = fmaf(df, df, d); }
        dist[t] = d;
    }
    __syncthreads();
    if (t == 0) {
        float mn = dist[0]; int arg = 0;
        for (int c = 1; c < 10; c++) if (dist[c] < mn) { mn = dist[c]; arg = c; }
        float sum = 0.f;
        for (int c = 0; c < 10; c++) sum += expf(-0.5f * (dist[c] - mn));
        smn = mn; ssum = sum; sarg = arg;
        atomicAdd(&cw[arg], 1.f);
        int pos = atomicAdd(&cls_cnt[arg], 1);
        cls_idx[arg * 256 + pos] = b;
    }
    __syncthreads();
    if (t < 10) {
        float es = -0.5f * (dist[t] - smn);
        float resp = expf(es) / ssum;
        out[b * 10 + t] = logf(fmaxf(resp, 1e-8f));
    }
    if (t < 48) {
        float v = zb[t] - centers[sarg * 48 + t];
        dvs[t] = v;
        dov[b * 48 + t] = v;
    }
    __syncthreads();
#pragma unroll
    for (int e = 0; e < 18; e++) {
        int cell = t + 128 * e;
        pairm[b * 2304 + cell] = dvs[cell / 48] * dvs[cell % 48];
    }
}

// ---------------- unified GMM tail: p4 (1710) + p3 (360) + m12 (10) ----------------
__global__ void k_gmm(const float* __restrict__ pairm, const float* __restrict__ dov,
                      const float* __restrict__ cw, const int* __restrict__ cls_cnt,
                      const int* __restrict__ cls_idx, const float* __restrict__ momw,
                      const float* __restrict__ gm1, const float* __restrict__ gm2,
                      const float* __restrict__ gm3, float* __restrict__ out) {
    __shared__ __align__(16) float smem[12544];      // 49 KB carve
    int blk = blockIdx.x;
    int t = threadIdx.x;

    if (blk < 1710) {
        // ---- p4: M4 = P^T P, triangular 128x128 tiles, analytic t4 ----
        float* Pp = smem;                 // 32*128
        float* Pq = smem + 4096;          // 32*128
        float* red = smem + 8192;         // 256
        int c = blk / 171;
        int rem = blk % 171;
        int pt = 0;
        while (rem >= 18 - pt) { rem -= 18 - pt; pt++; }
        int qt = pt + rem;
        int cnt = cls_cnt[c];
        const int* cidx = cls_idx + c * 256;
        int pi = t & 15, qi = t >> 4;
        int p0 = pt * 128 + pi * 8, q0 = qt * 128 + qi * 8;
        float acc[8][8];
#pragma unroll
        for (int e = 0; e < 8; e++)
#pragma unroll
            for (int f = 0; f < 8; f++) acc[e][f] = 0.f;
        for (int s0 = 0; s0 < cnt; s0 += 32) {
            int sc = min(32, cnt - s0);
            __syncthreads();
            for (int i = t; i < sc * 32; i += 256) {
                int row = i >> 5, u = i & 31;
                const float* src = pairm + (size_t)cidx[s0 + row] * 2304;
                ((float4*)Pp)[row * 32 + u] = ((const float4*)(src + pt * 128))[u];
                ((float4*)Pq)[row * 32 + u] = ((const float4*)(src + qt * 128))[u];
            }
            __syncthreads();
            for (int s = 0; s < sc; s++) {
                float4 a0 = *(const float4*)&Pp[s * 128 + pi * 8];
                float4 a1 = *(const float4*)&Pp[s * 128 + pi * 8 + 4];
                float4 b0 = *(const float4*)&Pq[s * 128 + qi * 8];
                float4 b1 = *(const float4*)&Pq[s * 128 + qi * 8 + 4];
                float pa[8] = {a0.x, a0.y, a0.z, a0.w, a1.x, a1.y, a1.z, a1.w};
                float pb[8] = {b0.x, b0.y, b0.z, b0.w, b1.x, b1.y, b1.z, b1.w};
#pragma unroll
                for (int e = 0; e < 8; e++)
#pragma unroll
                    for (int f = 0; f < 8; f++)
                        acc[e][f] = fmaf(pa[e], pb[f], acc[e][f]);
            }
        }
        float T1 = sroot_quarter(1.f), T3 = sroot_quarter(3.f);
        float cwn = cw[c] * (1.f / 256.f);
        bool diag = (pt == qt);
        float p4c = 0.f;
#pragma unroll
        for (int e = 0; e < 8; e++) {
            int p = p0 + e;
            int ip = p / 48, jp = p % 48;
            float mwp = momw[jp];
#pragma unroll
            for (int f = 0; f < 8; f++) {
                int q = q0 + f;
                int kq = q / 48, lq = q % 48;
                int g = ((ip == jp) && (kq == lq))
                      + ((ip == kq) && (jp == lq))
                      + ((ip == lq) && (jp == kq));
                float t4v = (g == 0) ? 0.f : ((g == 1) ? T1 : T3);
                float d4 = sroot_quarter(acc[e][f]) - t4v;
                float wgt = diag ? momw[lq] : (momw[lq] + mwp);
                p4c += wgt * d4 * d4;
            }
        }
        p4c *= cwn;
        red[t] = p4c; __syncthreads();
        for (int off = 128; off > 0; off >>= 1) { if (t < off) red[t] += red[t + off]; __syncthreads(); }
        if (t == 0) atomicAdd(&out[2563], red[0]);

    } else if (blk < 2070) {
        // ---- p3: m3 = pair^T * do per class ----
        float* Pl = smem;                 // 64*64
        float* Dl = smem + 4096;          // 64*48
        float* red = smem + 7168;         // 256
        int bb = blk - 1710;
        int c = bb / 36, pt = bb % 36;
        int cnt = cls_cnt[c];
        const int* cidx = cls_idx + c * 256;
        int pl = t >> 2, kq = t & 3;
        float acc[12];
#pragma unroll
        for (int m = 0; m < 12; m++) acc[m] = 0.f;
        for (int s0 = 0; s0 < cnt; s0 += 64) {
            int sc = min(64, cnt - s0);
            __syncthreads();
            for (int i = t; i < sc * 16; i += 256) {
                int row = i >> 4, u = i & 15;
                ((float4*)Pl)[row * 16 + u] =
                    ((const float4*)(pairm + (size_t)cidx[s0 + row] * 2304 + pt * 64))[u];
            }
            for (int i = t; i < sc * 12; i += 256) {
                int row = i / 12, u = i % 12;
                ((float4*)Dl)[row * 12 + u] =
                    ((const float4*)(dov + (size_t)cidx[s0 + row] * 48))[u];
            }
            __syncthreads();
            for (int s = 0; s < sc; s++) {
                float pa = Pl[s * 64 + pl];
                float4 d0 = *(const float4*)&Dl[s * 48 + kq * 12];
                float4 d1 = *(const float4*)&Dl[s * 48 + kq * 12 + 4];
                float4 d2 = *(const float4*)&Dl[s * 48 + kq * 12 + 8];
                acc[0]  = fmaf(pa, d0.x, acc[0]);  acc[1]  = fmaf(pa, d0.y, acc[1]);
                acc[2]  = fmaf(pa, d0.z, acc[2]);  acc[3]  = fmaf(pa, d0.w, acc[3]);
                acc[4]  = fmaf(pa, d1.x, acc[4]);  acc[5]  = fmaf(pa, d1.y, acc[5]);
                acc[6]  = fmaf(pa, d1.z, acc[6]);  acc[7]  = fmaf(pa, d1.w, acc[7]);
                acc[8]  = fmaf(pa, d2.x, acc[8]);  acc[9]  = fmaf(pa, d2.y, acc[9]);
                acc[10] = fmaf(pa, d2.z, acc[10]); acc[11] = fmaf(pa, d2.w, acc[11]);
            }
        }
        float cwn = cw[c] * (1.f / 256.f);
        int p = pt * 64 + pl;
        float p3c = 0.f;
#pragma unroll
        for (int m = 0; m < 12; m++) {
            int k = kq * 12 + m;
            float d3 = sroot_cbrt(acc[m]) - sroot_cbrt(gm3[p * 48 + k]);
            p3c += momw[k] * d3 * d3;
        }
        p3c *= cwn;
        red[t] = p3c; __syncthreads();
        for (int off = 128; off > 0; off >>= 1) { if (t < off) red[t] += red[t + off]; __syncthreads(); }
        if (t == 0) atomicAdd(&out[2562], red[0]);

    } else {
        // ---- m1/m2 -> p1, p2 (one block per class) ----
        float* ds = smem;                 // up to 256*48
        float* red = smem + 12288;        // 256
        int c = blk - 2070;
        int cnt = cls_cnt[c];
        const int* cidx = cls_idx + c * 256;
        for (int i = t; i < cnt * 48; i += 256)
            ds[i] = dov[(size_t)cidx[i / 48] * 48 + (i % 48)];
        __syncthreads();
        float denom = cw[c] + 1e-7f;
        float cwn = cw[c] * (1.f / 256.f);
        float p2c = 0.f;
        for (int r = 0; r < 9; r++) {
            int cell = t + 256 * r;
            int i = cell / 48, j = cell % 48;
            float acc = 0.f;
            for (int s = 0; s < cnt; s++) acc = fmaf(ds[s * 48 + i], ds[s * 48 + j], acc);
            float m2v = acc / denom;
            float d2 = sroot_half(m2v) - sroot_half(gm2[cell]);
            p2c += cwn * momw[j] * d2 * d2;
        }
        red[t] = p2c; __syncthreads();
        for (int off = 128; off > 0; off >>= 1) { if (t < off) red[t] += red[t + off]; __syncthreads(); }
        if (t == 0) atomicAdd(&out[2561], red[0]);
        if (t < 48) {
            float acc = 0.f;
            for (int s = 0; s < cnt; s++) acc += ds[s * 48 + t];
            float m1v = acc / denom;
            float d1 = m1v - gm1[t];
            atomicAdd(&out[2560], cwn * momw[t] * d1 * d1);
        }
    }
}

// ---------------- launch ----------------
extern "C" void kernel_launch(void* const* d_in, const int* in_sizes, int n_in,
                              void* d_out, int out_size, void* d_ws, size_t ws_size,
                              hipStream_t stream) {
    const float* x    = (const float*)d_in[0];
    const float* c1w  = (const float*)d_in[1];
    const float* c1b  = (const float*)d_in[2];
    const float* c2w  = (const float*)d_in[3];
    const float* c2b  = (const float*)d_in[4];
    const float* f1w  = (const float*)d_in[5];
    const float* f1b  = (const float*)d_in[6];
    const float* f2w  = (const float*)d_in[7];
    const float* f2b  = (const float*)d_in[8];
    const float* f3w  = (const float*)d_in[9];
    const float* f3b  = (const float*)d_in[10];
    const float* cen  = (const float*)d_in[11];
    const float* momw = (const float*)d_in[12];
    const float* gm1  = (const float*)d_in[13];
    const float* gm2  = (const float*)d_in[14];
    const float* gm3  = (const float*)d_in[15];

    float* ws      = (float*)d_ws;
    float* h1      = ws + OFF_H1;
    float* pairm   = ws + OFF_PAIR;
    float* fc1p    = ws + OFF_FC1P;
    float* wT      = ws + OFF_WT;
    float* pooled  = ws + OFF_POOL;
    float* dov     = ws + OFF_DO;
    float* cwp     = ws + OFF_CW;
    int*   iws     = (int*)(ws + OFF_INT);
    int*   cls_cnt = iws;
    int*   cls_idx = iws + 16;
    float* out     = (float*)d_out;

    k_conv1<<<7200, 256, 0, stream>>>(x, c1w, c1b, h1, cwp, cls_cnt, out);
    k_conv2<<<1568, 256, 0, stream>>>(h1, c2w, c2b, pooled);
    k_wtrans<<<1568, 256, 0, stream>>>(f1w, wT);     // AFTER conv2: wT aliases h1
    k_fc1<<<1024, 256, 0, stream>>>(pooled, wT, fc1p);
    k_fc23a<<<256, 128, 0, stream>>>(fc1p, f1b, f2w, f2b, f3w, f3b, cen, out,
                                     dov, pairm, cwp, cls_cnt, cls_idx);
    k_gmm<<<2080, 256, 0, stream>>>(pairm, dov, cwp, cls_cnt, cls_idx, momw,
                                    gm1, gm2, gm3, out);
}

// Round 7
// 317.515 us; speedup vs baseline: 1.1459x; 1.1459x over previous
//
#include <hip/hip_runtime.h>
#include <math.h>

// ---------------- problem constants ----------------
#define BATCH   256
#define NCLS    10
#define DIM     48

// ---------------- workspace layout (float elements) ----------------
// Timeline: conv1 writes h1b [0,3686400) + wprep [4.4M,4.43M).
// conv2 reads h1b/wprep, writes pooled. After conv2, h1b region is dead and is
// reused by: pairm [0,589824), fc1p [602112,2699264), wT [2699264,4304896).
#define OFF_H1B   0            // 256*900*64 ushort = 3,686,400 floats
#define OFF_PAIR  0            // 256*2304 = 589824 (written by k_fc23a)
#define OFF_FC1P  602112       // 64*256*128 = 2097152 (ends 2699264)
#define OFF_WT    2699264      // 12544*128 = 1605632 (ends 4304896)
#define OFF_WPH   4400000      // 18432 ushort (conv2 w hi frags) — free gap
#define OFF_WPL   4420000      // 18432 ushort (conv2 w lo frags)
#define OFF_POOL  7372800      // 256*12544 = 3211264
#define OFF_DO    10596352     // 256*48
#define OFF_CW    10608640     // 16
#define OFF_INT   10608656     // ints: cls_cnt[16], cls_idx[2560]

typedef __attribute__((ext_vector_type(8))) short short8;
typedef __attribute__((ext_vector_type(4))) float floatx4;
typedef unsigned short u16;
typedef unsigned int u32;

// ---------------- bf16 helpers (RNE) ----------------
__device__ __forceinline__ u16 f2bf(float v) {
    u32 u = __float_as_uint(v);
    return (u16)((u + 0x7fffu + ((u >> 16) & 1u)) >> 16);
}
__device__ __forceinline__ float bf2f(u16 h) {
    return __uint_as_float(((u32)h) << 16);
}

// ---------------- signed-root helpers ----------------
__device__ __forceinline__ float sroot_half(float m) {
    float s = (m < 0.f) ? -1.f : 1.f;
    return s * (sqrtf(fabsf(m) + 0.25f) - 0.5f);
}
__device__ __forceinline__ float sroot_cbrt(float m) {
    float s = (m < 0.f) ? -1.f : 1.f;
    return s * (cbrtf(fabsf(m) + 0.19245008973f) - 0.57735026919f);
}
__device__ __forceinline__ float sroot_quarter(float m) {
    float s = (m < 0.f) ? -1.f : 1.f;
    return s * (sqrtf(sqrtf(fabsf(m) + 0.15749013123f)) - 0.62996052494f);
}

// ------- conv1 + relu -> h1b NHWC bf16 hi/lo; + init + conv2-weight prep -------
// blocks [0,28800): conv1 (8 positions x 32 oc per block). block 28800: w-prep.
__global__ void k_conv1(const float* __restrict__ x, const float* __restrict__ w,
                        const float* __restrict__ bias, u16* __restrict__ h1b,
                        const float* __restrict__ c2w, u16* __restrict__ wph,
                        u16* __restrict__ wpl, float* __restrict__ cw,
                        int* __restrict__ cls_cnt, float* __restrict__ out) {
    int blk = blockIdx.x;
    int tid = threadIdx.x;
    if (blk == 28800) {
        // wprep layout: [s(9)][icq(4)][oc(64)][icr(8)]  (B-fragment register order)
        for (int i = tid; i < 18432; i += 256) {
            int icr = i & 7, rest = i >> 3;
            int oc = rest & 63, rest2 = rest >> 6;
            int icq = rest2 & 3, s = rest2 >> 2;
            int ic = icq * 8 + icr;
            float v = c2w[(oc * 32 + ic) * 9 + s];
            u16 hi = f2bf(v);
            wph[i] = hi;
            wpl[i] = f2bf(v - bf2f(hi));
        }
        return;
    }
    if (blk == 0) {
        if (tid < 16) { cw[tid] = 0.f; cls_cnt[tid] = 0; }
        else if (tid < 20) out[2560 + tid - 16] = 0.f;
    }
    int oc = tid & 31, pg = tid >> 5;
    int pos = blk * 8 + pg;                // [0, 230400)
    int b = pos / 900, rem = pos % 900;
    int y = rem / 30, xx = rem % 30;
    float acc = bias[oc];
    const float* wo = w + oc * 27;
    const float* xb = x + b * 3072;
#pragma unroll
    for (int ic = 0; ic < 3; ic++) {
        const float* xp = xb + ic * 1024 + y * 32 + xx;
#pragma unroll
        for (int ky = 0; ky < 3; ky++)
#pragma unroll
            for (int kx = 0; kx < 3; kx++)
                acc = fmaf(xp[ky * 32 + kx], wo[ic * 9 + ky * 3 + kx], acc);
    }
    acc = fmaxf(acc, 0.f);
    u16 hi = f2bf(acc);
    h1b[(size_t)pos * 64 + oc]      = hi;
    h1b[(size_t)pos * 64 + 32 + oc] = f2bf(acc - bf2f(hi));
}

// -------- conv2 + relu + 2x2 maxpool via MFMA bf16x2 (3-term, fp32-grade) --------
// 9 shifted GEMMs, K=32 ic per shift. Block = (b, 2x2 spatial quadrant):
// pooled 7x7 tile, M = 49 groups x 4 (dy,dx) = 196 rows -> 13 M-tiles of 16.
// LDS: 16x16 input positions x 144 B (32 ic hi + 32 ic lo bf16, padded).
__global__ void k_conv2(const u16* __restrict__ h1b, const u16* __restrict__ wph,
                        const u16* __restrict__ wpl, const float* __restrict__ bias,
                        float* __restrict__ pooled) {
    __shared__ u16 hs[256 * 72];           // 36864 B
    int blk = blockIdx.x;                  // 1024 blocks
    int b = blk >> 2, sub = blk & 3;
    int hy = sub >> 1, hx = sub & 1;
    int row0 = hy * 14, col0 = hx * 14;    // input window base (16x16 of 30x30)
    int tid = threadIdx.x;
    // stage: 256 positions x 128 B -> padded 144 B rows
    for (int i = tid; i < 2048; i += 256) {
        int p = i >> 3, c8 = i & 7;
        int r = p >> 4, cc = p & 15;
        size_t gp = (size_t)b * 900 + (size_t)(row0 + r) * 30 + col0 + cc;
        *(uint4*)(&hs[p * 72 + c8 * 8]) = *(const uint4*)(&h1b[gp * 64 + c8 * 8]);
    }
    int wv = tid >> 6, lane = tid & 63;
    int n = lane & 15, quad = lane >> 4;
    int ocb = wv * 16 + n;
    float bv = bias[ocb];
    // B fragments (hi/lo) for all 9 shifts, held in registers
    short8 bh[9], bl[9];
#pragma unroll
    for (int s = 0; s < 9; s++) {
        int off = (((s * 4 + quad) * 64) + ocb) * 8;
        bh[s] = *(const short8*)(&wph[off]);
        bl[s] = *(const short8*)(&wpl[off]);
    }
    __syncthreads();
    int ml = lane & 15;                    // A-row within M-tile
    for (int t = 0; t < 13; t++) {
        int gA = t * 4 + (ml >> 2);        // pooled group of this A-row
        int d = ml & 3;
        int gc = (gA < 49) ? gA : 0;       // clamp garbage rows (t=12 tail)
        int py = gc / 7, px = gc % 7;
        int rb = 2 * py + (d >> 1), cb = 2 * px + (d & 1);
        floatx4 acc = {0.f, 0.f, 0.f, 0.f};
#pragma unroll
        for (int s = 0; s < 9; s++) {
            int ky = s / 3, kx = s % 3;
            int pos = (rb + ky) * 16 + cb + kx;
            short8 ah = *(const short8*)(&hs[pos * 72 + quad * 8]);
            short8 al = *(const short8*)(&hs[pos * 72 + 32 + quad * 8]);
            acc = __builtin_amdgcn_mfma_f32_16x16x32_bf16(ah, bh[s], acc, 0, 0, 0);
            acc = __builtin_amdgcn_mfma_f32_16x16x32_bf16(ah, bl[s], acc, 0, 0, 0);
            acc = __builtin_amdgcn_mfma_f32_16x16x32_bf16(al, bh[s], acc, 0, 0, 0);
        }
        // C rows quad*4+reg = the 4 pre-pool members of pooled group G
        int G = t * 4 + quad;
        if (G < 49) {
            float v = fmaxf(fmaxf(acc.x, acc.y), fmaxf(acc.z, acc.w));
            v = fmaxf(v + bv, 0.f);
            int pyg = hy * 7 + G / 7, pxg = hx * 7 + G % 7;
            pooled[(size_t)b * 12544 + ocb * 196 + pyg * 14 + pxg] = v;
        }
    }
}

// ---------------- W transpose: wT[k][n] = w[n][k] (AFTER conv2: wT aliases h1b) ----------------
__global__ void k_wtrans(const float* __restrict__ w, float* __restrict__ wT) {
    __shared__ float tile[32][33];
    int kb = blockIdx.x % 392, nb = blockIdx.x / 392;
    int tid = threadIdx.x;
    int tx = tid & 31, ty = tid >> 5;
    int k0 = kb * 32, n0 = nb * 32;
#pragma unroll
    for (int r = 0; r < 4; r++)
        tile[tx][ty * 4 + r] = w[(n0 + ty * 4 + r) * 12544 + k0 + tx];
    __syncthreads();
#pragma unroll
    for (int r = 0; r < 4; r++)
        wT[(k0 + ty * 4 + r) * 128 + n0 + tx] = tile[ty * 4 + r][tx];
}

// ---------------- fc1 K-split GEMM, coalesced W via wT, broadcast A ----------------
__global__ void k_fc1(const float* __restrict__ pooled, const float* __restrict__ wT,
                      float* __restrict__ fc1p) {
    __shared__ __align__(16) float Alds[16 * 196];   // 12.5 KB
    int blk = blockIdx.x;
    int sg = blk >> 6, kc = blk & 63;
    int tid = threadIdx.x;
    int m0 = sg * 16, k0 = kc * 196;
    for (int i = tid; i < 784; i += 256) {           // 16 rows * 49 float4
        int m = i / 49, u = i % 49;
        ((float4*)Alds)[m * 49 + u] = ((const float4*)(pooled + (m0 + m) * 12544 + k0))[u];
    }
    __syncthreads();
    int n2 = tid & 63, mg = tid >> 6;
    const float* wp = wT + (size_t)k0 * 128 + n2;
    const float* arow = Alds + mg * 4 * 196;
    float acc[4][2];
#pragma unroll
    for (int j = 0; j < 4; j++) { acc[j][0] = 0.f; acc[j][1] = 0.f; }
    for (int k = 0; k < 196; k += 2) {
        float wa0 = wp[k * 128],        wb0 = wp[k * 128 + 64];
        float wa1 = wp[(k + 1) * 128],  wb1 = wp[(k + 1) * 128 + 64];
#pragma unroll
        for (int j = 0; j < 4; j++) {
            float2 av = *(const float2*)(arow + j * 196 + k);
            acc[j][0] = fmaf(av.x, wa0, acc[j][0]);
            acc[j][0] = fmaf(av.y, wa1, acc[j][0]);
            acc[j][1] = fmaf(av.x, wb0, acc[j][1]);
            acc[j][1] = fmaf(av.y, wb1, acc[j][1]);
        }
    }
#pragma unroll
    for (int j = 0; j < 4; j++) {
        int m = m0 + mg * 4 + j;
        fc1p[kc * 32768 + m * 128 + n2]      = acc[j][0];
        fc1p[kc * 32768 + m * 128 + n2 + 64] = acc[j][1];
    }
}

// ------- fc1-reduce + fc2 + fc3 + assignment + pair row, fused per-sample -------
__global__ void k_fc23a(const float* __restrict__ fc1p, const float* __restrict__ f1b,
                        const float* __restrict__ w2, const float* __restrict__ b2,
                        const float* __restrict__ w3, const float* __restrict__ b3,
                        const float* __restrict__ centers, float* __restrict__ out,
                        float* __restrict__ dov, float* __restrict__ pairm,
                        float* __restrict__ cw, int* __restrict__ cls_cnt,
                        int* __restrict__ cls_idx) {
    __shared__ float a[128], h[128], zb[48], dvs[48];
    __shared__ float dist[10];
    __shared__ float smn, ssum;
    __shared__ int sarg;
    int b = blockIdx.x, t = threadIdx.x;
    float s0 = f1b[t];
    for (int p = 0; p < 64; p++) s0 += fc1p[p * 32768 + b * 128 + t];
    a[t] = fmaxf(s0, 0.f);
    __syncthreads();
    float s = b2[t];
    const float* wr = w2 + t * 128;
#pragma unroll 4
    for (int k = 0; k < 128; k++) s = fmaf(wr[k], a[k], s);
    h[t] = fmaxf(s, 0.f);
    __syncthreads();
    if (t < 48) {
        float s3 = b3[t];
        const float* wr3 = w3 + t * 128;
#pragma unroll 4
        for (int k = 0; k < 128; k++) s3 = fmaf(wr3[k], h[k], s3);
        zb[t] = s3;
    }
    __syncthreads();
    if (t < 10) {
        float d = 0.f;
        const float* cc = centers + t * 48;
        for (int k = 0; k < 48; k++) { float df = zb[k] - cc[k]; d = fmaf(df, df, d); }
        dist[t] = d;
    }
    __syncthreads();
    if (t == 0) {
        float mn = dist[0]; int arg = 0;
        for (int c = 1; c < 10; c++) if (dist[c] < mn) { mn = dist[c]; arg = c; }
        float sum = 0.f;
        for (int c = 0; c < 10; c++) sum += expf(-0.5f * (dist[c] - mn));
        smn = mn; ssum = sum; sarg = arg;
        atomicAdd(&cw[arg], 1.f);
        int pos = atomicAdd(&cls_cnt[arg], 1);
        cls_idx[arg * 256 + pos] = b;
    }
    __syncthreads();
    if (t < 10) {
        float es = -0.5f * (dist[t] - smn);
        float resp = expf(es) / ssum;
        out[b * 10 + t] = logf(fmaxf(resp, 1e-8f));
    }
    if (t < 48) {
        float v = zb[t] - centers[sarg * 48 + t];
        dvs[t] = v;
        dov[b * 48 + t] = v;
    }
    __syncthreads();
#pragma unroll
    for (int e = 0; e < 18; e++) {
        int cell = t + 128 * e;
        pairm[b * 2304 + cell] = dvs[cell / 48] * dvs[cell % 48];
    }
}

// ---------------- unified GMM tail: p4 (1710) + p3 (360) + m12 (10) ----------------
__global__ void k_gmm(const float* __restrict__ pairm, const float* __restrict__ dov,
                      const float* __restrict__ cw, const int* __restrict__ cls_cnt,
                      const int* __restrict__ cls_idx, const float* __restrict__ momw,
                      const float* __restrict__ gm1, const float* __restrict__ gm2,
                      const float* __restrict__ gm3, float* __restrict__ out) {
    __shared__ __align__(16) float smem[12544];      // 49 KB carve
    int blk = blockIdx.x;
    int t = threadIdx.x;

    if (blk < 1710) {
        // ---- p4: M4 = P^T P, triangular 128x128 tiles, analytic t4 ----
        float* Pp = smem;                 // 32*128
        float* Pq = smem + 4096;          // 32*128
        float* red = smem + 8192;         // 256
        int c = blk / 171;
        int rem = blk % 171;
        int pt = 0;
        while (rem >= 18 - pt) { rem -= 18 - pt; pt++; }
        int qt = pt + rem;
        int cnt = cls_cnt[c];
        const int* cidx = cls_idx + c * 256;
        int pi = t & 15, qi = t >> 4;
        int p0 = pt * 128 + pi * 8, q0 = qt * 128 + qi * 8;
        float acc[8][8];
#pragma unroll
        for (int e = 0; e < 8; e++)
#pragma unroll
            for (int f = 0; f < 8; f++) acc[e][f] = 0.f;
        for (int s0 = 0; s0 < cnt; s0 += 32) {
            int sc = min(32, cnt - s0);
            __syncthreads();
            for (int i = t; i < sc * 32; i += 256) {
                int row = i >> 5, u = i & 31;
                const float* src = pairm + (size_t)cidx[s0 + row] * 2304;
                ((float4*)Pp)[row * 32 + u] = ((const float4*)(src + pt * 128))[u];
                ((float4*)Pq)[row * 32 + u] = ((const float4*)(src + qt * 128))[u];
            }
            __syncthreads();
            for (int s = 0; s < sc; s++) {
                float4 a0 = *(const float4*)&Pp[s * 128 + pi * 8];
                float4 a1 = *(const float4*)&Pp[s * 128 + pi * 8 + 4];
                float4 b0 = *(const float4*)&Pq[s * 128 + qi * 8];
                float4 b1 = *(const float4*)&Pq[s * 128 + qi * 8 + 4];
                float pa[8] = {a0.x, a0.y, a0.z, a0.w, a1.x, a1.y, a1.z, a1.w};
                float pb[8] = {b0.x, b0.y, b0.z, b0.w, b1.x, b1.y, b1.z, b1.w};
#pragma unroll
                for (int e = 0; e < 8; e++)
#pragma unroll
                    for (int f = 0; f < 8; f++)
                        acc[e][f] = fmaf(pa[e], pb[f], acc[e][f]);
            }
        }
        float T1 = sroot_quarter(1.f), T3 = sroot_quarter(3.f);
        float cwn = cw[c] * (1.f / 256.f);
        bool diag = (pt == qt);
        float p4c = 0.f;
#pragma unroll
        for (int e = 0; e < 8; e++) {
            int p = p0 + e;
            int ip = p / 48, jp = p % 48;
            float mwp = momw[jp];
#pragma unroll
            for (int f = 0; f < 8; f++) {
                int q = q0 + f;
                int kq = q / 48, lq = q % 48;
                int g = ((ip == jp) && (kq == lq))
                      + ((ip == kq) && (jp == lq))
                      + ((ip == lq) && (jp == kq));
                float t4v = (g == 0) ? 0.f : ((g == 1) ? T1 : T3);
                float d4 = sroot_quarter(acc[e][f]) - t4v;
                float wgt = diag ? momw[lq] : (momw[lq] + mwp);
                p4c += wgt * d4 * d4;
            }
        }
        p4c *= cwn;
        red[t] = p4c; __syncthreads();
        for (int off = 128; off > 0; off >>= 1) { if (t < off) red[t] += red[t + off]; __syncthreads(); }
        if (t == 0) atomicAdd(&out[2563], red[0]);

    } else if (blk < 2070) {
        // ---- p3: m3 = pair^T * do per class ----
        float* Pl = smem;                 // 64*64
        float* Dl = smem + 4096;          // 64*48
        float* red = smem + 7168;         // 256
        int bb = blk - 1710;
        int c = bb / 36, pt = bb % 36;
        int cnt = cls_cnt[c];
        const int* cidx = cls_idx + c * 256;
        int pl = t >> 2, kq = t & 3;
        float acc[12];
#pragma unroll
        for (int m = 0; m < 12; m++) acc[m] = 0.f;
        for (int s0 = 0; s0 < cnt; s0 += 64) {
            int sc = min(64, cnt - s0);
            __syncthreads();
            for (int i = t; i < sc * 16; i += 256) {
                int row = i >> 4, u = i & 15;
                ((float4*)Pl)[row * 16 + u] =
                    ((const float4*)(pairm + (size_t)cidx[s0 + row] * 2304 + pt * 64))[u];
            }
            for (int i = t; i < sc * 12; i += 256) {
                int row = i / 12, u = i % 12;
                ((float4*)Dl)[row * 12 + u] =
                    ((const float4*)(dov + (size_t)cidx[s0 + row] * 48))[u];
            }
            __syncthreads();
            for (int s = 0; s < sc; s++) {
                float pa = Pl[s * 64 + pl];
                float4 d0 = *(const float4*)&Dl[s * 48 + kq * 12];
                float4 d1 = *(const float4*)&Dl[s * 48 + kq * 12 + 4];
                float4 d2 = *(const float4*)&Dl[s * 48 + kq * 12 + 8];
                acc[0]  = fmaf(pa, d0.x, acc[0]);  acc[1]  = fmaf(pa, d0.y, acc[1]);
                acc[2]  = fmaf(pa, d0.z, acc[2]);  acc[3]  = fmaf(pa, d0.w, acc[3]);
                acc[4]  = fmaf(pa, d1.x, acc[4]);  acc[5]  = fmaf(pa, d1.y, acc[5]);
                acc[6]  = fmaf(pa, d1.z, acc[6]);  acc[7]  = fmaf(pa, d1.w, acc[7]);
                acc[8]  = fmaf(pa, d2.x, acc[8]);  acc[9]  = fmaf(pa, d2.y, acc[9]);
                acc[10] = fmaf(pa, d2.z, acc[10]); acc[11] = fmaf(pa, d2.w, acc[11]);
            }
        }
        float cwn = cw[c] * (1.f / 256.f);
        int p = pt * 64 + pl;
        float p3c = 0.f;
#pragma unroll
        for (int m = 0; m < 12; m++) {
            int k = kq * 12 + m;
            float d3 = sroot_cbrt(acc[m]) - sroot_cbrt(gm3[p * 48 + k]);
            p3c += momw[k] * d3 * d3;
        }
        p3c *= cwn;
        red[t] = p3c; __syncthreads();
        for (int off = 128; off > 0; off >>= 1) { if (t < off) red[t] += red[t + off]; __syncthreads(); }
        if (t == 0) atomicAdd(&out[2562], red[0]);

    } else {
        // ---- m1/m2 -> p1, p2 (one block per class) ----
        float* ds = smem;                 // up to 256*48
        float* red = smem + 12288;        // 256
        int c = blk - 2070;
        int cnt = cls_cnt[c];
        const int* cidx = cls_idx + c * 256;
        for (int i = t; i < cnt * 48; i += 256)
            ds[i] = dov[(size_t)cidx[i / 48] * 48 + (i % 48)];
        __syncthreads();
        float denom = cw[c] + 1e-7f;
        float cwn = cw[c] * (1.f / 256.f);
        float p2c = 0.f;
        for (int r = 0; r < 9; r++) {
            int cell = t + 256 * r;
            int i = cell / 48, j = cell % 48;
            float acc = 0.f;
            for (int s = 0; s < cnt; s++) acc = fmaf(ds[s * 48 + i], ds[s * 48 + j], acc);
            float m2v = acc / denom;
            float d2 = sroot_half(m2v) - sroot_half(gm2[cell]);
            p2c += cwn * momw[j] * d2 * d2;
        }
        red[t] = p2c; __syncthreads();
        for (int off = 128; off > 0; off >>= 1) { if (t < off) red[t] += red[t + off]; __syncthreads(); }
        if (t == 0) atomicAdd(&out[2561], red[0]);
        if (t < 48) {
            float acc = 0.f;
            for (int s = 0; s < cnt; s++) acc += ds[s * 48 + t];
            float m1v = acc / denom;
            float d1 = m1v - gm1[t];
            atomicAdd(&out[2560], cwn * momw[t] * d1 * d1);
        }
    }
}

// ---------------- launch ----------------
extern "C" void kernel_launch(void* const* d_in, const int* in_sizes, int n_in,
                              void* d_out, int out_size, void* d_ws, size_t ws_size,
                              hipStream_t stream) {
    const float* x    = (const float*)d_in[0];
    const float* c1w  = (const float*)d_in[1];
    const float* c1b  = (const float*)d_in[2];
    const float* c2w  = (const float*)d_in[3];
    const float* c2b  = (const float*)d_in[4];
    const float* f1w  = (const float*)d_in[5];
    const float* f1b  = (const float*)d_in[6];
    const float* f2w  = (const float*)d_in[7];
    const float* f2b  = (const float*)d_in[8];
    const float* f3w  = (const float*)d_in[9];
    const float* f3b  = (const float*)d_in[10];
    const float* cen  = (const float*)d_in[11];
    const float* momw = (const float*)d_in[12];
    const float* gm1  = (const float*)d_in[13];
    const float* gm2  = (const float*)d_in[14];
    const float* gm3  = (const float*)d_in[15];

    float* ws      = (float*)d_ws;
    u16*   h1b     = (u16*)(ws + OFF_H1B);
    float* pairm   = ws + OFF_PAIR;
    float* fc1p    = ws + OFF_FC1P;
    float* wT      = ws + OFF_WT;
    u16*   wph     = (u16*)(ws + OFF_WPH);
    u16*   wpl     = (u16*)(ws + OFF_WPL);
    float* pooled  = ws + OFF_POOL;
    float* dov     = ws + OFF_DO;
    float* cwp     = ws + OFF_CW;
    int*   iws     = (int*)(ws + OFF_INT);
    int*   cls_cnt = iws;
    int*   cls_idx = iws + 16;
    float* out     = (float*)d_out;

    k_conv1<<<28801, 256, 0, stream>>>(x, c1w, c1b, h1b, c2w, wph, wpl,
                                       cwp, cls_cnt, out);
    k_conv2<<<1024, 256, 0, stream>>>(h1b, wph, wpl, c2b, pooled);
    k_wtrans<<<1568, 256, 0, stream>>>(f1w, wT);     // AFTER conv2: wT aliases h1b
    k_fc1<<<1024, 256, 0, stream>>>(pooled, wT, fc1p);
    k_fc23a<<<256, 128, 0, stream>>>(fc1p, f1b, f2w, f2b, f3w, f3b, cen, out,
                                     dov, pairm, cwp, cls_cnt, cls_idx);
    k_gmm<<<2080, 256, 0, stream>>>(pairm, dov, cwp, cls_cnt, cls_idx, momw,
                                    gm1, gm2, gm3, out);
}